// Round 2
// baseline (3321.998 us; speedup 1.0000x reference)
//
#include <hip/hip_runtime.h>
#include <hip/hip_bf16.h>
#include <math.h>

#define T_STEPS 512
#define BATCH   1024

__device__ __forceinline__ float sigm(float z)  { return 1.0f / (1.0f + expf(-z)); }
__device__ __forceinline__ float tanh_(float z) { return 1.0f - 2.0f / (expf(2.0f * z) + 1.0f); }

#define FMA4(acc, wv, hv)                      \
    acc = fmaf((wv).x, (hv).x, acc);           \
    acc = fmaf((wv).y, (hv).y, acc);           \
    acc = fmaf((wv).z, (hv).z, acc);           \
    acc = fmaf((wv).w, (hv).w, acc)

// ---------------------------------------------------------------------------
// Fully fused BiLSTM: one block per batch element, 256 threads (4 waves).
// Phase A: layer-1 reverse -> hr[513][64] in LDS (slot 512 = zeros).
// Phase B: layer-1 forward (waves 0-1) pipelined with layer-2 forward
//          (waves 2-3), skew 1 step, 2 barriers/step.
// Phase C: layer-2 reverse single step @ t=T-1 (zero init state) + MLP head.
// No global workspace at all.
// ---------------------------------------------------------------------------
__global__ __launch_bounds__(256, 1) void bilstm_fused_kernel(
    const float* __restrict__ x,       // [B, T] (F==1)
    const float* __restrict__ wih1f, const float* __restrict__ whh1f, const float* __restrict__ b1f,
    const float* __restrict__ wih1r, const float* __restrict__ whh1r, const float* __restrict__ b1r,
    const float* __restrict__ wih2f, const float* __restrict__ whh2f, const float* __restrict__ b2f,
    const float* __restrict__ wih2r, const float* __restrict__ b2r,
    const float* __restrict__ w_fc1, const float* __restrict__ b_fc1,
    const float* __restrict__ w_out, const float* __restrict__ b_out,
    float* __restrict__ out)           // [B]
{
    __shared__ __align__(16) float hr[513 * 64];     // 128.25 KB
    __shared__ __align__(16) float xbuf[T_STEPS];
    __shared__ __align__(16) float hfbuf[2][64];
    __shared__ __align__(16) float fobuf[128];
    __shared__ __align__(16) float h2buf[32];
    __shared__ __align__(16) float g2buf[4][32];
    __shared__ __align__(16) float gA[4][64];
    __shared__ __align__(16) float lastbuf[64];

    const int b   = blockIdx.x;
    const int tid = threadIdx.x;
    const int u   = tid & 63;

    for (int i = tid; i < T_STEPS; i += 256) xbuf[i] = x[(size_t)b * T_STEPS + i];
    if (tid < 64) { hr[512 * 64 + tid] = 0.0f; hfbuf[1][tid] = 0.0f; }
    if (tid < 32) h2buf[tid] = 0.0f;

    // ======================= Phase A: layer-1 reverse ======================
    {
        const int gate = tid >> 6;   // 0:i 1:f 2:g 3:o ; row = tid
        float4 w[16];
#pragma unroll
        for (int q = 0; q < 16; ++q) w[q] = *(const float4*)(whh1r + tid * 64 + q * 4);
        const float wi = wih1r[tid];
        const float bb = b1r[tid];
        float c = 0.0f;
        __syncthreads();   // covers xbuf / hr-zero / hfbuf / h2buf inits too

        for (int t = T_STEPS - 1; t >= 0; --t) {
            const float xt = xbuf[t];
            float a0 = fmaf(xt, wi, bb), a1 = 0.0f;
            const float* hp = hr + (t + 1) * 64;
#pragma unroll
            for (int q = 0; q < 16; q += 2) {
                const float4 h0 = *(const float4*)(hp + q * 4);
                const float4 h1 = *(const float4*)(hp + q * 4 + 4);
                FMA4(a0, w[q], h0);
                FMA4(a1, w[q + 1], h1);
            }
            const float z = a0 + a1;
            gA[gate][u] = (gate == 2) ? tanh_(z) : sigm(z);
            __syncthreads();
            if (gate == 0) {
                c = fmaf(gA[1][u], c, gA[0][u] * gA[2][u]);
                hr[t * 64 + u] = gA[3][u] * tanh_(c);
            }
            __syncthreads();
        }
    }

    // ========== Phase B: layer-1 forward + layer-2 forward (skew 1) ========
    {
        const int wv = tid >> 6;
        const int u2 = tid & 31;
        const int g2 = (tid - 128) >> 5;       // valid for wv>=2 only
        float4 wA[16], wB[16];                 // waves 0-1: whh1f rows
        float4 w2p[32], w2r[8];                // waves 2-3: wih2f + whh2f rows
        float wiA = 0.f, wiB = 0.f, bA = 0.f, bB = 0.f, b2v = 0.f;
        if (wv < 2) {
            const int rA = wv * 64 + u;        // i (wv0) / f (wv1)
            const int rB = 128 + wv * 64 + u;  // g (wv0) / o (wv1)
#pragma unroll
            for (int q = 0; q < 16; ++q) {
                wA[q] = *(const float4*)(whh1f + rA * 64 + q * 4);
                wB[q] = *(const float4*)(whh1f + rB * 64 + q * 4);
            }
            wiA = wih1f[rA]; wiB = wih1f[rB]; bA = b1f[rA]; bB = b1f[rB];
        } else {
            const int r2 = tid - 128;          // layer-2 gate row, 0..127
#pragma unroll
            for (int q = 0; q < 32; ++q) w2p[q] = *(const float4*)(wih2f + r2 * 128 + q * 4);
#pragma unroll
            for (int q = 0; q < 8; ++q)  w2r[q] = *(const float4*)(whh2f + r2 * 32 + q * 4);
            b2v = b2f[r2];
        }

        float c1 = 0.0f, c2 = 0.0f, si = 0.0f, tg = 0.0f;

        for (int t = 0; t <= T_STEPS; ++t) {
            // ---------------- Body 1 ----------------
            if (wv < 2) {
                if (t < T_STEPS) {
                    const float xt = xbuf[t];
                    float p0 = fmaf(xt, wiA, bA), p1 = 0.0f;
                    float q0 = fmaf(xt, wiB, bB), q1 = 0.0f;
                    const float* hp = hfbuf[(t + 1) & 1];   // h_f(t-1)
#pragma unroll
                    for (int q = 0; q < 16; q += 2) {
                        const float4 h0 = *(const float4*)(hp + q * 4);
                        const float4 h1 = *(const float4*)(hp + q * 4 + 4);
                        FMA4(p0, wA[q], h0);
                        FMA4(p1, wA[q + 1], h1);
                        FMA4(q0, wB[q], h0);
                        FMA4(q1, wB[q + 1], h1);
                    }
                    const float z0 = p0 + p1, z1 = q0 + q1;
                    if (wv == 1) { fobuf[u] = sigm(z0); fobuf[64 + u] = sigm(z1); }
                    else         { si = sigm(z0); tg = tanh_(z1); }
                }
            } else if (t >= 1) {
                const int s = t - 1;                        // layer-2 step
                float a0 = b2v, a1 = 0.0f, a2 = 0.0f, a3 = 0.0f;
                const float* hfp = hfbuf[s & 1];            // h_f(s)
                const float* hrp = hr + s * 64;             // h_r(s)
#pragma unroll
                for (int q = 0; q < 16; q += 2) {
                    const float4 h0 = *(const float4*)(hfp + q * 4);
                    const float4 h1 = *(const float4*)(hfp + q * 4 + 4);
                    FMA4(a0, w2p[q], h0);
                    FMA4(a1, w2p[q + 1], h1);
                }
#pragma unroll
                for (int q = 0; q < 16; q += 2) {
                    const float4 h0 = *(const float4*)(hrp + q * 4);
                    const float4 h1 = *(const float4*)(hrp + q * 4 + 4);
                    FMA4(a2, w2p[16 + q], h0);
                    FMA4(a3, w2p[17 + q], h1);
                }
#pragma unroll
                for (int q = 0; q < 8; q += 2) {
                    const float4 h0 = *(const float4*)(h2buf + q * 4);
                    const float4 h1 = *(const float4*)(h2buf + q * 4 + 4);
                    FMA4(a0, w2r[q], h0);
                    FMA4(a1, w2r[q + 1], h1);
                }
                const float z2 = (a0 + a1) + (a2 + a3);
                g2buf[g2][u2] = (g2 == 2) ? tanh_(z2) : sigm(z2);
            }
            __syncthreads();   // B1
            // ---------------- Body 2 ----------------
            if (tid < 64) {
                if (t < T_STEPS) {
                    c1 = fmaf(fobuf[u], c1, si * tg);
                    hfbuf[t & 1][u] = fobuf[64 + u] * tanh_(c1);
                }
            } else if (tid >= 128 && tid < 160) {
                if (t >= 1) {
                    c2 = fmaf(g2buf[1][u2], c2, g2buf[0][u2] * g2buf[2][u2]);
                    h2buf[u2] = g2buf[3][u2] * tanh_(c2);
                }
            }
            __syncthreads();   // B2
        }
    }

    // ===== Phase C: layer-2 reverse single step @ t=T-1 + MLP head =========
    {
        if (tid < 128) {
            const float* hfl = hfbuf[(T_STEPS - 1) & 1];    // h_f(T-1)
            const float* hrl = hr + (T_STEPS - 1) * 64;     // h_r(T-1)
            float a0 = b2r[tid], a1 = 0.0f;
#pragma unroll
            for (int q = 0; q < 16; ++q) {
                const float4 wv1 = *(const float4*)(wih2r + tid * 128 + q * 4);
                const float4 hv  = *(const float4*)(hfl + q * 4);
                FMA4(a0, wv1, hv);
            }
#pragma unroll
            for (int q = 0; q < 16; ++q) {
                const float4 wv2 = *(const float4*)(wih2r + tid * 128 + 64 + q * 4);
                const float4 hv  = *(const float4*)(hrl + q * 4);
                FMA4(a1, wv2, hv);
            }
            const float z  = a0 + a1;
            const int   gg = tid >> 5, uu = tid & 31;
            g2buf[gg][uu] = (gg == 2) ? tanh_(z) : sigm(z);
        }
        __syncthreads();
        if (tid < 32) {
            const float cr = g2buf[0][tid] * g2buf[2][tid];   // c0 = 0: f-gate irrelevant
            lastbuf[32 + tid] = g2buf[3][tid] * tanh_(cr);    // h_r2(T-1)
            lastbuf[tid]      = h2buf[tid];                   // h_f2(T-1)
        }
        __syncthreads();
        if (tid < 64) {
            float acc = b_fc1[tid];
#pragma unroll
            for (int q = 0; q < 16; ++q) {
                const float4 wvv = *(const float4*)(w_fc1 + tid * 64 + q * 4);
                const float4 lv  = *(const float4*)(lastbuf + q * 4);
                FMA4(acc, wvv, lv);
            }
            float prod = fmaxf(acc, 0.0f) * w_out[tid];
#pragma unroll
            for (int s2 = 1; s2 < 64; s2 <<= 1) prod += __shfl_xor(prod, s2, 64);
            if (tid == 0) out[b] = sigm(prod + b_out[0]);
        }
    }
}

// ---------------------------------------------------------------------------
extern "C" void kernel_launch(void* const* d_in, const int* in_sizes, int n_in,
                              void* d_out, int out_size, void* d_ws, size_t ws_size,
                              hipStream_t stream) {
    const float* x     = (const float*)d_in[0];
    const float* wih1f = (const float*)d_in[1];
    const float* whh1f = (const float*)d_in[2];
    const float* b1f   = (const float*)d_in[3];
    const float* wih1r = (const float*)d_in[4];
    const float* whh1r = (const float*)d_in[5];
    const float* b1r   = (const float*)d_in[6];
    const float* wih2f = (const float*)d_in[7];
    const float* whh2f = (const float*)d_in[8];
    const float* b2f   = (const float*)d_in[9];
    const float* wih2r = (const float*)d_in[10];
    // d_in[11] = whh2r: unused (layer-2 reverse runs exactly one step from zero state)
    const float* b2r   = (const float*)d_in[12];
    const float* w_fc1 = (const float*)d_in[13];
    const float* b_fc1 = (const float*)d_in[14];
    const float* w_out = (const float*)d_in[15];
    const float* b_out = (const float*)d_in[16];
    float* out = (float*)d_out;

    bilstm_fused_kernel<<<dim3(BATCH), dim3(256), 0, stream>>>(
        x, wih1f, whh1f, b1f, wih1r, whh1r, b1r,
        wih2f, whh2f, b2f, wih2r, b2r,
        w_fc1, b_fc1, w_out, b_out, out);
}

// Round 3
// 1752.694 us; speedup vs baseline: 1.8954x; 1.8954x over previous
//
#include <hip/hip_runtime.h>
#include <hip/hip_bf16.h>
#include <math.h>

#define T_STEPS 512
#define BATCH   1024

__device__ __forceinline__ float fast_sigm(float z) {
    return __fdividef(1.0f, 1.0f + __expf(-z));
}
__device__ __forceinline__ float fast_tanh(float z) {
    return fmaf(2.0f, __fdividef(1.0f, 1.0f + __expf(-2.0f * z)), -1.0f);
}
// gate: 0=i(sig) 1=f(sig) 2=g(tanh) 3=o(sig), branch-free via cndmask
__device__ __forceinline__ float gate_fn(int g, float z) {
    const bool tg = (g == 2);
    const float s = fast_sigm(tg ? 2.0f * z : z);
    return tg ? fmaf(2.0f, s, -1.0f) : s;
}
__device__ __forceinline__ unsigned short f2bf(float f) {
    unsigned int u = __float_as_uint(f);
    u += 0x7fffu + ((u >> 16) & 1u);
    return (unsigned short)(u >> 16);
}
__device__ __forceinline__ float bflo(unsigned int d) { return __uint_as_float(d << 16); }
__device__ __forceinline__ float bfhi(unsigned int d) { return __uint_as_float(d & 0xffff0000u); }

#define FMA4(acc, wv, hv)                      \
    acc = fmaf((wv).x, (hv).x, acc);           \
    acc = fmaf((wv).y, (hv).y, acc);           \
    acc = fmaf((wv).z, (hv).z, acc);           \
    acc = fmaf((wv).w, (hv).w, acc)

// 8 bf16 (one uint4) dotted with 2 float4 weight regs
#define BF8(acc0, acc1, dv, wq0, wq1)                          \
    acc0 = fmaf(bflo((dv).x), (wq0).x, acc0);                  \
    acc0 = fmaf(bfhi((dv).x), (wq0).y, acc0);                  \
    acc0 = fmaf(bflo((dv).y), (wq0).z, acc0);                  \
    acc0 = fmaf(bfhi((dv).y), (wq0).w, acc0);                  \
    acc1 = fmaf(bflo((dv).z), (wq1).x, acc1);                  \
    acc1 = fmaf(bfhi((dv).z), (wq1).y, acc1);                  \
    acc1 = fmaf(bflo((dv).w), (wq1).z, acc1);                  \
    acc1 = fmaf(bfhi((dv).w), (wq1).w, acc1)

// ---------------------------------------------------------------------------
// Fully fused BiLSTM, one block per batch element, 256 threads (4 waves).
// LDS ~69.6 KB -> 2 blocks/CU (2 waves/SIMD). 1 barrier per recurrence step:
// gate combination is wave-local via __shfl_xor(16/32/48); h state is
// double-buffered with write-parity chosen so reads/writes never collide.
// Phase A: layer-1 reverse; h_r archived to bf16 LDS (64 KB), fp32 frontier.
// Phase B: layer-1 forward (waves 0-1) + layer-2 forward skewed 1 step
//          (waves 2-3, reading the bf16 archive).
// Phase C: layer-2 reverse single step @ t=T-1 (zero init state) + MLP head.
// ---------------------------------------------------------------------------
__global__ __launch_bounds__(256, 2) void bilstm_fused_kernel(
    const float* __restrict__ x,
    const float* __restrict__ wih1f, const float* __restrict__ whh1f, const float* __restrict__ b1f,
    const float* __restrict__ wih1r, const float* __restrict__ whh1r, const float* __restrict__ b1r,
    const float* __restrict__ wih2f, const float* __restrict__ whh2f, const float* __restrict__ b2f,
    const float* __restrict__ wih2r, const float* __restrict__ b2r,
    const float* __restrict__ w_fc1, const float* __restrict__ b_fc1,
    const float* __restrict__ w_out, const float* __restrict__ b_out,
    float* __restrict__ out)
{
    __shared__ __align__(16) unsigned short hr16[T_STEPS * 64];  // 64 KB bf16 archive
    __shared__ __align__(16) float xbuf[T_STEPS];                // 2 KB
    __shared__ __align__(16) float hrfb[2][64];                  // layer-1 rev frontier
    __shared__ __align__(16) float hfbuf[2][64];                 // layer-1 fwd frontier
    __shared__ __align__(16) float h2buf[2][32];                 // layer-2 fwd frontier
    __shared__ __align__(16) float g2c[4][32];                   // phase-C gate staging
    __shared__ __align__(16) float lastbuf[64];

    const int b   = blockIdx.x;
    const int tid = threadIdx.x;

    for (int i = tid; i < T_STEPS; i += 256) xbuf[i] = x[(size_t)b * T_STEPS + i];
    if (tid < 64) { hrfb[0][tid] = 0.0f; hfbuf[1][tid] = 0.0f; }
    if (tid < 32) h2buf[1][tid] = 0.0f;

    float4 W[40];

    // ======================= Phase A: layer-1 reverse ======================
    {
        const int w   = tid >> 6;       // wave -> units [16w, 16w+16)
        const int l   = tid & 63;
        const int ul  = l & 15;
        const int g   = l >> 4;         // gate
        const int row = g * 64 + w * 16 + ul;
#pragma unroll
        for (int q = 0; q < 16; ++q) W[q] = *(const float4*)(whh1r + row * 64 + q * 4);
        const float wi = wih1r[row];
        const float bb = b1r[row];
        float c = 0.0f;
        __syncthreads();   // covers xbuf / frontier zero-init

        for (int t = T_STEPS - 1; t >= 0; --t) {
            const float4* hp = (const float4*)hrfb[(t + 1) & 1];
            float a0 = fmaf(xbuf[t], wi, bb), a1 = 0.0f, a2 = 0.0f, a3 = 0.0f;
#pragma unroll
            for (int q = 0; q < 16; q += 4) {
                FMA4(a0, W[q],     hp[q]);
                FMA4(a1, W[q + 1], hp[q + 1]);
                FMA4(a2, W[q + 2], hp[q + 2]);
                FMA4(a3, W[q + 3], hp[q + 3]);
            }
            const float z = (a0 + a1) + (a2 + a3);
            const float v = gate_fn(g, z);
            const float sf = __shfl_xor(v, 16, 64);
            const float tg = __shfl_xor(v, 32, 64);
            const float so = __shfl_xor(v, 48, 64);
            if (g == 0) {
                c = fmaf(sf, c, v * tg);
                const float h = so * fast_tanh(c);
                hrfb[t & 1][w * 16 + ul] = h;
                hr16[t * 64 + w * 16 + ul] = f2bf(h);
            }
            __syncthreads();
        }
    }

    // ========== Phase B: layer-1 forward + layer-2 forward (skew 1) ========
    {
        const int wv = tid >> 6;
        const int l  = tid & 63;
        float wiA = 0.f, wiB = 0.f, bA = 0.f, bB = 0.f, b2v = 0.f;
        int u1 = 0, p1 = 0, u2 = 0, g2 = 0;
        if (wv < 2) {
            u1 = wv * 32 + (l & 31);
            p1 = l >> 5;                       // 0: {i,g}, 1: {f,o}
            const int rA = p1 * 64 + u1;       // i or f
            const int rB = 128 + p1 * 64 + u1; // g or o
#pragma unroll
            for (int q = 0; q < 16; ++q) {
                W[q]      = *(const float4*)(whh1f + rA * 64 + q * 4);
                W[16 + q] = *(const float4*)(whh1f + rB * 64 + q * 4);
            }
            wiA = wih1f[rA]; wiB = wih1f[rB]; bA = b1f[rA]; bB = b1f[rB];
        } else {
            u2 = (wv - 2) * 16 + (l & 15);
            g2 = l >> 4;
            const int row = g2 * 32 + u2;      // layer-2 gate row
#pragma unroll
            for (int q = 0; q < 32; ++q) W[q] = *(const float4*)(wih2f + row * 128 + q * 4);
#pragma unroll
            for (int q = 0; q < 8; ++q) W[32 + q] = *(const float4*)(whh2f + row * 32 + q * 4);
            b2v = b2f[row];
        }

        float c1 = 0.0f, c2 = 0.0f;

        for (int t = 0; t <= T_STEPS; ++t) {
            if (wv < 2) {
                if (t < T_STEPS) {
                    const float4* hp = (const float4*)hfbuf[(t + 1) & 1];  // h_f(t-1)
                    const float xt = xbuf[t];
                    float p0 = fmaf(xt, wiA, bA), pp1 = 0.0f;
                    float q0 = fmaf(xt, wiB, bB), qq1 = 0.0f;
#pragma unroll
                    for (int q = 0; q < 16; q += 2) {
                        const float4 h0 = hp[q], h1 = hp[q + 1];
                        FMA4(p0,  W[q],          h0);
                        FMA4(pp1, W[q + 1],      h1);
                        FMA4(q0,  W[16 + q],     h0);
                        FMA4(qq1, W[16 + q + 1], h1);
                    }
                    const float z0 = p0 + pp1, z1 = q0 + qq1;
                    // p1==0: v0=sig(i), v1=tanh(g) ; p1==1: v0=sig(f), v1=sig(o)
                    const float v0 = fast_sigm(z0);
                    const float v1 = (p1 == 0) ? fast_tanh(z1) : fast_sigm(z1);
                    const float o0 = __shfl_xor(v0, 32, 64);   // sig(f) -> p0
                    const float o1 = __shfl_xor(v1, 32, 64);   // sig(o) -> p0
                    if (p1 == 0) {
                        c1 = fmaf(o0, c1, v0 * v1);
                        hfbuf[t & 1][u1] = o1 * fast_tanh(c1);
                    }
                }
            } else {
                if (t >= 1) {
                    const int s = t - 1;
                    const float4* hf  = (const float4*)hfbuf[(t + 1) & 1];  // h_f(s)
                    const float4* h2p = (const float4*)h2buf[t & 1];        // h2(s-1)
                    const uint4*  hrp = (const uint4*)(hr16 + s * 64);      // h_r(s) bf16
                    float a0 = b2v, a1 = 0.0f, a2 = 0.0f, a3 = 0.0f;
#pragma unroll
                    for (int q = 0; q < 16; q += 2) {
                        FMA4(a0, W[q],     hf[q]);
                        FMA4(a1, W[q + 1], hf[q + 1]);
                    }
#pragma unroll
                    for (int q = 0; q < 8; ++q) {
                        const uint4 dv = hrp[q];
                        BF8(a2, a3, dv, W[16 + 2 * q], W[17 + 2 * q]);
                    }
#pragma unroll
                    for (int q = 0; q < 8; q += 2) {
                        FMA4(a0, W[32 + q],     h2p[q]);
                        FMA4(a1, W[32 + q + 1], h2p[q + 1]);
                    }
                    const float z = (a0 + a1) + (a2 + a3);
                    const float v = gate_fn(g2, z);
                    const float sf = __shfl_xor(v, 16, 64);
                    const float tg = __shfl_xor(v, 32, 64);
                    const float so = __shfl_xor(v, 48, 64);
                    if (g2 == 0) {
                        c2 = fmaf(sf, c2, v * tg);
                        h2buf[(t + 1) & 1][u2] = so * fast_tanh(c2);  // h2(s) -> buf[s&1]
                    }
                }
            }
            __syncthreads();
        }
    }

    // ===== Phase C: layer-2 reverse single step @ t=T-1 + MLP head =========
    {
        if (tid < 128) {
            const float4* hfl = (const float4*)hfbuf[1];               // h_f(511)
            const uint4*  hrl = (const uint4*)(hr16 + 511 * 64);       // h_r(511)
            const float4* wr  = (const float4*)(wih2r + tid * 128);
            float a0 = b2r[tid], a1 = 0.0f, a2 = 0.0f, a3 = 0.0f;
#pragma unroll
            for (int q = 0; q < 16; q += 2) {
                FMA4(a0, wr[q],     hfl[q]);
                FMA4(a1, wr[q + 1], hfl[q + 1]);
            }
#pragma unroll
            for (int q = 0; q < 8; ++q) {
                const uint4 dv = hrl[q];
                BF8(a2, a3, dv, wr[16 + 2 * q], wr[17 + 2 * q]);
            }
            const float z = (a0 + a1) + (a2 + a3);
            g2c[tid >> 5][tid & 31] = gate_fn(tid >> 5, z);
        }
        __syncthreads();
        if (tid < 32) {
            const float cr = g2c[0][tid] * g2c[2][tid];     // c0 = 0: f-gate irrelevant
            lastbuf[32 + tid] = g2c[3][tid] * fast_tanh(cr);
            lastbuf[tid]      = h2buf[1][tid];              // h2_f(511)
        }
        __syncthreads();
        if (tid < 64) {
            const float4* lv = (const float4*)lastbuf;
            float acc = b_fc1[tid];
#pragma unroll
            for (int q = 0; q < 16; ++q) {
                const float4 wvv = *(const float4*)(w_fc1 + tid * 64 + q * 4);
                FMA4(acc, wvv, lv[q]);
            }
            float prod = fmaxf(acc, 0.0f) * w_out[tid];
#pragma unroll
            for (int s2 = 1; s2 < 64; s2 <<= 1) prod += __shfl_xor(prod, s2, 64);
            if (tid == 0) out[b] = fast_sigm(prod + b_out[0]);
        }
    }
}

// ---------------------------------------------------------------------------
extern "C" void kernel_launch(void* const* d_in, const int* in_sizes, int n_in,
                              void* d_out, int out_size, void* d_ws, size_t ws_size,
                              hipStream_t stream) {
    const float* x     = (const float*)d_in[0];
    const float* wih1f = (const float*)d_in[1];
    const float* whh1f = (const float*)d_in[2];
    const float* b1f   = (const float*)d_in[3];
    const float* wih1r = (const float*)d_in[4];
    const float* whh1r = (const float*)d_in[5];
    const float* b1r   = (const float*)d_in[6];
    const float* wih2f = (const float*)d_in[7];
    const float* whh2f = (const float*)d_in[8];
    const float* b2f   = (const float*)d_in[9];
    const float* wih2r = (const float*)d_in[10];
    // d_in[11] = whh2r unused: layer-2 reverse runs exactly one step from zero state
    const float* b2r   = (const float*)d_in[12];
    const float* w_fc1 = (const float*)d_in[13];
    const float* b_fc1 = (const float*)d_in[14];
    const float* w_out = (const float*)d_in[15];
    const float* b_out = (const float*)d_in[16];
    float* out = (float*)d_out;

    bilstm_fused_kernel<<<dim3(BATCH), dim3(256), 0, stream>>>(
        x, wih1f, whh1f, b1f, wih1r, whh1r, b1r,
        wih2f, whh2f, b2f, wih2r, b2r,
        w_fc1, b_fc1, w_out, b_out, out);
}

// Round 4
// 1211.645 us; speedup vs baseline: 2.7417x; 1.4465x over previous
//
#include <hip/hip_runtime.h>
#include <hip/hip_bf16.h>
#include <math.h>

#define T_STEPS 512
#define BATCH   1024
#define NB      16
#define NBLK    (BATCH / NB)   // 64 blocks for the MFMA version

typedef __attribute__((ext_vector_type(8))) short short8;
typedef __attribute__((ext_vector_type(4))) float f32x4;

__device__ __forceinline__ float fast_sigm(float z) {
    return __fdividef(1.0f, 1.0f + __expf(-z));
}
__device__ __forceinline__ float fast_tanh(float z) {
    return fmaf(2.0f, __fdividef(1.0f, 1.0f + __expf(-2.0f * z)), -1.0f);
}
__device__ __forceinline__ unsigned short f2bf(float f) {
    unsigned int u = __float_as_uint(f);
    u += 0x7fffu + ((u >> 16) & 1u);
    return (unsigned short)(u >> 16);
}
__device__ __forceinline__ float bf2f(unsigned short s) {
    return __uint_as_float(((unsigned int)s) << 16);
}
__device__ __forceinline__ short8 ldfrag(const float* __restrict__ p) {
    short8 r;
#pragma unroll
    for (int e = 0; e < 8; ++e) r[e] = (short)f2bf(p[e]);
    return r;
}

// ===========================================================================
// MFMA version: 64 blocks x 512 threads (8 waves), NB=16 batches per block.
// Recurrent matvec z[16,256] = h[16,64] x WhhT via mfma_f32_16x16x32_bf16.
// Weights live in VGPRs as B-fragments; h-tile in LDS [batch][unit] bf16 with
// +8-unit pad (bank spread). C-layout (verified): col=lane&15,
// row=(lane>>4)*4+reg -> all 4 gates of one (batch,unit) are register-local.
// Phase A: layer-1 reverse, h_r archived to d_ws (bf16, 1MB/block).
// Phase B: layer-1 fwd (waves 0-3) + layer-2 fwd skewed 1 step (waves 4-7,
//          hr prefetched from d_ws one step ahead).
// Phase C: layer-2 reverse single step @ t=T-1 (zero state) + MLP head.
// ===========================================================================
__global__ __launch_bounds__(512, 2) void bilstm_mfma_kernel(
    const float* __restrict__ x,
    const float* __restrict__ wih1f, const float* __restrict__ whh1f, const float* __restrict__ b1f,
    const float* __restrict__ wih1r, const float* __restrict__ whh1r, const float* __restrict__ b1r,
    const float* __restrict__ wih2f, const float* __restrict__ whh2f, const float* __restrict__ b2f,
    const float* __restrict__ wih2r, const float* __restrict__ b2r,
    const float* __restrict__ w_fc1, const float* __restrict__ b_fc1,
    const float* __restrict__ w_out, const float* __restrict__ b_out,
    unsigned short* __restrict__ arch,    // [NBLK][T][NB][64] bf16
    float* __restrict__ out)
{
    __shared__ __align__(16) float xT[T_STEPS][20];        // x transposed, padded
    __shared__ __align__(16) short hrT[2][16][72];         // h_r frontier dbuf (bf16, pad 72)
    __shared__ __align__(16) short hfT[2][16][72];         // h_f frontier dbuf
    __shared__ __align__(16) short h2T[2][16][40];         // h2 frontier dbuf (pad 40)
    __shared__ __align__(16) float exch[2][2][16][16];     // L2 gate exchange (g,o)
    __shared__ __align__(16) float actsC[4][16][32];
    __shared__ __align__(16) float lastT[16][68];
    __shared__ __align__(16) float zzT[16][68];

    const int blk = blockIdx.x;
    const int tid = threadIdx.x;
    const int wv  = tid >> 6;
    const int l   = tid & 63;
    const int lg  = l >> 4;    // lane k-group 0..3
    const int lr  = l & 15;    // lane row/col within tile
    unsigned short* __restrict__ archb = arch + (size_t)blk * T_STEPS * NB * 64;

    // ---- load x transposed (coalesced reads) + zero-init tiles
    for (int i = tid; i < T_STEPS * NB; i += 512) {
        const int b = i >> 9, t = i & 511;
        xT[t][b] = x[((size_t)(blk * NB + b)) * T_STEPS + t];
    }
    for (int i = tid; i < 16 * 72; i += 512) { hrT[0][i / 72][i % 72] = 0; hfT[1][i / 72][i % 72] = 0; }
    for (int i = tid; i < 16 * 40; i += 512) { h2T[1][i / 40][i % 40] = 0; }
    __syncthreads();

    // ======================= Phase A: layer-1 reverse ======================
    {
        short8 Bw[4][2]; float wihv[4], bvv[4];
        if (wv < 4) {
#pragma unroll
            for (int g = 0; g < 4; ++g) {
                const int row = g * 64 + wv * 16 + lr;
                Bw[g][0] = ldfrag(whh1r + row * 64 + lg * 8);
                Bw[g][1] = ldfrag(whh1r + row * 64 + 32 + lg * 8);
                wihv[g] = wih1r[row]; bvv[g] = b1r[row];
            }
        }
        float c[4] = {0.f, 0.f, 0.f, 0.f};
        for (int t = T_STEPS - 1; t >= 0; --t) {
            if (wv < 4) {
                const int rp = (t + 1) & 1;
                const short8 a0 = *(const short8*)&hrT[rp][lr][lg * 8];
                const short8 a1 = *(const short8*)&hrT[rp][lr][32 + lg * 8];
                f32x4 z[4];
#pragma unroll
                for (int g = 0; g < 4; ++g) {
                    f32x4 acc = {0.f, 0.f, 0.f, 0.f};
                    acc = __builtin_amdgcn_mfma_f32_16x16x32_bf16(a0, Bw[g][0], acc, 0, 0, 0);
                    acc = __builtin_amdgcn_mfma_f32_16x16x32_bf16(a1, Bw[g][1], acc, 0, 0, 0);
                    z[g] = acc;
                }
                const float4 x4 = *(const float4*)&xT[t][lg * 4];
                const float xa[4] = {x4.x, x4.y, x4.z, x4.w};
#pragma unroll
                for (int j = 0; j < 4; ++j) {
                    const float vi = fast_sigm(z[0][j] + fmaf(xa[j], wihv[0], bvv[0]));
                    const float vf = fast_sigm(z[1][j] + fmaf(xa[j], wihv[1], bvv[1]));
                    const float vg = fast_tanh(z[2][j] + fmaf(xa[j], wihv[2], bvv[2]));
                    const float vo = fast_sigm(z[3][j] + fmaf(xa[j], wihv[3], bvv[3]));
                    c[j] = fmaf(vf, c[j], vi * vg);
                    const float h = vo * fast_tanh(c[j]);
                    const unsigned short hb = f2bf(h);
                    hrT[t & 1][lg * 4 + j][wv * 16 + lr] = (short)hb;
                    archb[((size_t)t * NB + lg * 4 + j) * 64 + wv * 16 + lr] = hb;
                }
            }
            __syncthreads();
        }
    }

    // ========== Phase B: layer-1 forward + layer-2 forward (skew 1) ========
    {
        short8 Bw[4][2]; float wihv[4], bvv[4];   // waves 0-3
        short8 B2[2][5]; float b2v[2];            // waves 4-7
        int p = 0, isGO = 0;
        if (wv < 4) {
#pragma unroll
            for (int g = 0; g < 4; ++g) {
                const int row = g * 64 + wv * 16 + lr;
                Bw[g][0] = ldfrag(whh1f + row * 64 + lg * 8);
                Bw[g][1] = ldfrag(whh1f + row * 64 + 32 + lg * 8);
                wihv[g] = wih1f[row]; bvv[g] = b1f[row];
            }
        } else {
            p = (wv - 4) >> 1; isGO = (wv - 4) & 1;
#pragma unroll
            for (int ti = 0; ti < 2; ++ti) {
                const int gate = isGO * 2 + ti;      // {i,f} or {g,o}
                const int row  = gate * 32 + p * 16 + lr;
                B2[ti][0] = ldfrag(wih2f + row * 128 + lg * 8);
                B2[ti][1] = ldfrag(wih2f + row * 128 + 32 + lg * 8);
                B2[ti][2] = ldfrag(wih2f + row * 128 + 64 + lg * 8);
                B2[ti][3] = ldfrag(wih2f + row * 128 + 96 + lg * 8);
                B2[ti][4] = ldfrag(whh2f + row * 32 + lg * 8);
                b2v[ti] = b2f[row];
            }
        }
        float c1[4] = {0.f, 0.f, 0.f, 0.f};
        float c2[4] = {0.f, 0.f, 0.f, 0.f};
        float vi2[4], vf2[4];
        short8 nxt0 = {}, nxt1 = {};
        if (wv >= 4) {   // prefetch hr(0)
            const unsigned short* pp = archb + (size_t)lr * 64 + lg * 8;
            nxt0 = *(const short8*)pp;
            nxt1 = *(const short8*)(pp + 32);
        }
        for (int t = 0; t <= T_STEPS; ++t) {
            if (wv < 4) {
                if (t < T_STEPS) {
                    const int rp = (t + 1) & 1;   // h_f(t-1)
                    const short8 a0 = *(const short8*)&hfT[rp][lr][lg * 8];
                    const short8 a1 = *(const short8*)&hfT[rp][lr][32 + lg * 8];
                    f32x4 z[4];
#pragma unroll
                    for (int g = 0; g < 4; ++g) {
                        f32x4 acc = {0.f, 0.f, 0.f, 0.f};
                        acc = __builtin_amdgcn_mfma_f32_16x16x32_bf16(a0, Bw[g][0], acc, 0, 0, 0);
                        acc = __builtin_amdgcn_mfma_f32_16x16x32_bf16(a1, Bw[g][1], acc, 0, 0, 0);
                        z[g] = acc;
                    }
                    const float4 x4 = *(const float4*)&xT[t][lg * 4];
                    const float xa[4] = {x4.x, x4.y, x4.z, x4.w};
#pragma unroll
                    for (int j = 0; j < 4; ++j) {
                        const float vi = fast_sigm(z[0][j] + fmaf(xa[j], wihv[0], bvv[0]));
                        const float vf = fast_sigm(z[1][j] + fmaf(xa[j], wihv[1], bvv[1]));
                        const float vg = fast_tanh(z[2][j] + fmaf(xa[j], wihv[2], bvv[2]));
                        const float vo = fast_sigm(z[3][j] + fmaf(xa[j], wihv[3], bvv[3]));
                        c1[j] = fmaf(vf, c1[j], vi * vg);
                        const float h = vo * fast_tanh(c1[j]);
                        hfT[t & 1][lg * 4 + j][wv * 16 + lr] = (short)f2bf(h);
                    }
                }
            } else if (t >= 1) {
                const int s = t - 1;
                const short8 hr0 = nxt0, hr1 = nxt1;
                if (t <= T_STEPS - 1) {   // prefetch hr(t) for next iteration
                    const unsigned short* pp = archb + ((size_t)t * NB + lr) * 64 + lg * 8;
                    nxt0 = *(const short8*)pp;
                    nxt1 = *(const short8*)(pp + 32);
                }
                const short8 af0 = *(const short8*)&hfT[s & 1][lr][lg * 8];
                const short8 af1 = *(const short8*)&hfT[s & 1][lr][32 + lg * 8];
                const short8 ah2 = *(const short8*)&h2T[t & 1][lr][lg * 8];   // h2(s-1)
                f32x4 zt[2];
#pragma unroll
                for (int ti = 0; ti < 2; ++ti) {
                    f32x4 acc = {0.f, 0.f, 0.f, 0.f};
                    acc = __builtin_amdgcn_mfma_f32_16x16x32_bf16(af0, B2[ti][0], acc, 0, 0, 0);
                    acc = __builtin_amdgcn_mfma_f32_16x16x32_bf16(af1, B2[ti][1], acc, 0, 0, 0);
                    acc = __builtin_amdgcn_mfma_f32_16x16x32_bf16(hr0, B2[ti][2], acc, 0, 0, 0);
                    acc = __builtin_amdgcn_mfma_f32_16x16x32_bf16(hr1, B2[ti][3], acc, 0, 0, 0);
                    acc = __builtin_amdgcn_mfma_f32_16x16x32_bf16(ah2, B2[ti][4], acc, 0, 0, 0);
                    zt[ti] = acc;
                }
                if (isGO) {
#pragma unroll
                    for (int j = 0; j < 4; ++j) {
                        exch[p][0][lg * 4 + j][lr] = fast_tanh(zt[0][j] + b2v[0]);  // tanh(g)
                        exch[p][1][lg * 4 + j][lr] = fast_sigm(zt[1][j] + b2v[1]);  // sig(o)
                    }
                } else {
#pragma unroll
                    for (int j = 0; j < 4; ++j) {
                        vi2[j] = fast_sigm(zt[0][j] + b2v[0]);
                        vf2[j] = fast_sigm(zt[1][j] + b2v[1]);
                    }
                }
            }
            __syncthreads();   // B1: exch + hf writes visible
            if (wv >= 4 && !isGO && t >= 1) {
                const int s = t - 1;
#pragma unroll
                for (int j = 0; j < 4; ++j) {
                    const float g = exch[p][0][lg * 4 + j][lr];
                    const float o = exch[p][1][lg * 4 + j][lr];
                    c2[j] = fmaf(vf2[j], c2[j], vi2[j] * g);
                    const float h2 = o * fast_tanh(c2[j]);
                    h2T[s & 1][lg * 4 + j][p * 16 + lr] = (short)f2bf(h2);
                }
            }
            __syncthreads();   // B2: h2 writes visible
        }
    }

    // ===== Phase C: layer-2 reverse single step @ t=T-1 + MLP head =========
    {
        // C1: z_r = Wih2r . [hf(511); hr(511)] + b2r  (zero init state)
        const int rr = tid & 127;
        const int bq = tid >> 7;   // 0..3
        const float* __restrict__ wr = wih2r + rr * 128;
        const int gate = rr >> 5, un = rr & 31;
#pragma unroll
        for (int jb = 0; jb < 4; ++jb) {
            const int b = bq * 4 + jb;
            float a0 = b2r[rr], a1 = 0.f;
            const unsigned short* hrp = archb + ((size_t)(T_STEPS - 1) * NB + b) * 64;
#pragma unroll
            for (int ub = 0; ub < 8; ++ub) {
                const short8 hv = *(const short8*)&hfT[1][b][ub * 8];
                const short8 rv = *(const short8*)(hrp + ub * 8);
#pragma unroll
                for (int e = 0; e < 8; ++e) {
                    a0 = fmaf(wr[ub * 8 + e],      bf2f((unsigned short)hv[e]), a0);
                    a1 = fmaf(wr[64 + ub * 8 + e], bf2f((unsigned short)rv[e]), a1);
                }
            }
            const float zv = a0 + a1;
            actsC[gate][b][un] = (gate == 2) ? fast_tanh(zv) : fast_sigm(zv);
        }
        __syncthreads();
        // C2: c_r = sig(i)*tanh(g); h_r = sig(o)*tanh(c_r); build last = [h2f, h2r]
        {
            const int b = tid >> 5, u = tid & 31;
            const float cr = actsC[0][b][u] * actsC[2][b][u];
            lastT[b][32 + u] = actsC[3][b][u] * fast_tanh(cr);
            lastT[b][u]      = bf2f((unsigned short)h2T[1][b][u]);
        }
        __syncthreads();
        // C3: fc1 + relu + w_out
        {
            const int row = tid & 63, bg = tid >> 6;   // bg 0..7
            const float* __restrict__ wf = w_fc1 + row * 64;
#pragma unroll
            for (int jb = 0; jb < 2; ++jb) {
                const int b = bg * 2 + jb;
                float acc = b_fc1[row];
#pragma unroll
                for (int u4 = 0; u4 < 16; ++u4) {
                    const float4 lv = *(const float4*)&lastT[b][u4 * 4];
                    const float4 w4 = *(const float4*)&wf[u4 * 4];
                    acc = fmaf(w4.x, lv.x, acc);
                    acc = fmaf(w4.y, lv.y, acc);
                    acc = fmaf(w4.z, lv.z, acc);
                    acc = fmaf(w4.w, lv.w, acc);
                }
                zzT[b][row] = fmaxf(acc, 0.f) * w_out[row];
            }
        }
        __syncthreads();
        // C4: reduce + sigmoid
        if (tid < NB) {
            float s = 0.f;
#pragma unroll 8
            for (int r = 0; r < 64; ++r) s += zzT[tid][r];
            out[blk * NB + tid] = fast_sigm(s + b_out[0]);
        }
    }
}

// ===========================================================================
// Fallback (ws too small): round-3 kernel, LDS archive, 1024 x 256. Passing
// at 1753 us. Unchanged.
// ===========================================================================
__device__ __forceinline__ float gate_fn(int g, float z) {
    const bool tg = (g == 2);
    const float s = fast_sigm(tg ? 2.0f * z : z);
    return tg ? fmaf(2.0f, s, -1.0f) : s;
}
__device__ __forceinline__ float bflo(unsigned int d) { return __uint_as_float(d << 16); }
__device__ __forceinline__ float bfhi(unsigned int d) { return __uint_as_float(d & 0xffff0000u); }

#define FMA4(acc, wv, hv)                      \
    acc = fmaf((wv).x, (hv).x, acc);           \
    acc = fmaf((wv).y, (hv).y, acc);           \
    acc = fmaf((wv).z, (hv).z, acc);           \
    acc = fmaf((wv).w, (hv).w, acc)

#define BF8(acc0, acc1, dv, wq0, wq1)                          \
    acc0 = fmaf(bflo((dv).x), (wq0).x, acc0);                  \
    acc0 = fmaf(bfhi((dv).x), (wq0).y, acc0);                  \
    acc0 = fmaf(bflo((dv).y), (wq0).z, acc0);                  \
    acc0 = fmaf(bfhi((dv).y), (wq0).w, acc0);                  \
    acc1 = fmaf(bflo((dv).z), (wq1).x, acc1);                  \
    acc1 = fmaf(bfhi((dv).z), (wq1).y, acc1);                  \
    acc1 = fmaf(bflo((dv).w), (wq1).z, acc1);                  \
    acc1 = fmaf(bfhi((dv).w), (wq1).w, acc1)

__global__ __launch_bounds__(256, 2) void bilstm_fused_kernel(
    const float* __restrict__ x,
    const float* __restrict__ wih1f, const float* __restrict__ whh1f, const float* __restrict__ b1f,
    const float* __restrict__ wih1r, const float* __restrict__ whh1r, const float* __restrict__ b1r,
    const float* __restrict__ wih2f, const float* __restrict__ whh2f, const float* __restrict__ b2f,
    const float* __restrict__ wih2r, const float* __restrict__ b2r,
    const float* __restrict__ w_fc1, const float* __restrict__ b_fc1,
    const float* __restrict__ w_out, const float* __restrict__ b_out,
    float* __restrict__ out)
{
    __shared__ __align__(16) unsigned short hr16[T_STEPS * 64];
    __shared__ __align__(16) float xbuf[T_STEPS];
    __shared__ __align__(16) float hrfb[2][64];
    __shared__ __align__(16) float hfbuf[2][64];
    __shared__ __align__(16) float h2buf[2][32];
    __shared__ __align__(16) float g2c[4][32];
    __shared__ __align__(16) float lastbuf[64];

    const int b   = blockIdx.x;
    const int tid = threadIdx.x;

    for (int i = tid; i < T_STEPS; i += 256) xbuf[i] = x[(size_t)b * T_STEPS + i];
    if (tid < 64) { hrfb[0][tid] = 0.0f; hfbuf[1][tid] = 0.0f; }
    if (tid < 32) h2buf[1][tid] = 0.0f;

    float4 W[40];

    {
        const int w   = tid >> 6;
        const int l   = tid & 63;
        const int ul  = l & 15;
        const int g   = l >> 4;
        const int row = g * 64 + w * 16 + ul;
#pragma unroll
        for (int q = 0; q < 16; ++q) W[q] = *(const float4*)(whh1r + row * 64 + q * 4);
        const float wi = wih1r[row];
        const float bb = b1r[row];
        float c = 0.0f;
        __syncthreads();

        for (int t = T_STEPS - 1; t >= 0; --t) {
            const float4* hp = (const float4*)hrfb[(t + 1) & 1];
            float a0 = fmaf(xbuf[t], wi, bb), a1 = 0.0f, a2 = 0.0f, a3 = 0.0f;
#pragma unroll
            for (int q = 0; q < 16; q += 4) {
                FMA4(a0, W[q],     hp[q]);
                FMA4(a1, W[q + 1], hp[q + 1]);
                FMA4(a2, W[q + 2], hp[q + 2]);
                FMA4(a3, W[q + 3], hp[q + 3]);
            }
            const float z = (a0 + a1) + (a2 + a3);
            const float v = gate_fn(g, z);
            const float sf = __shfl_xor(v, 16, 64);
            const float tg = __shfl_xor(v, 32, 64);
            const float so = __shfl_xor(v, 48, 64);
            if (g == 0) {
                c = fmaf(sf, c, v * tg);
                const float h = so * fast_tanh(c);
                hrfb[t & 1][w * 16 + ul] = h;
                hr16[t * 64 + w * 16 + ul] = f2bf(h);
            }
            __syncthreads();
        }
    }

    {
        const int wv = tid >> 6;
        const int l  = tid & 63;
        float wiA = 0.f, wiB = 0.f, bA = 0.f, bB = 0.f, b2v = 0.f;
        int u1 = 0, p1 = 0, u2 = 0, g2 = 0;
        if (wv < 2) {
            u1 = wv * 32 + (l & 31);
            p1 = l >> 5;
            const int rA = p1 * 64 + u1;
            const int rB = 128 + p1 * 64 + u1;
#pragma unroll
            for (int q = 0; q < 16; ++q) {
                W[q]      = *(const float4*)(whh1f + rA * 64 + q * 4);
                W[16 + q] = *(const float4*)(whh1f + rB * 64 + q * 4);
            }
            wiA = wih1f[rA]; wiB = wih1f[rB]; bA = b1f[rA]; bB = b1f[rB];
        } else {
            u2 = (wv - 2) * 16 + (l & 15);
            g2 = l >> 4;
            const int row = g2 * 32 + u2;
#pragma unroll
            for (int q = 0; q < 32; ++q) W[q] = *(const float4*)(wih2f + row * 128 + q * 4);
#pragma unroll
            for (int q = 0; q < 8; ++q) W[32 + q] = *(const float4*)(whh2f + row * 32 + q * 4);
            b2v = b2f[row];
        }

        float c1 = 0.0f, c2 = 0.0f;

        for (int t = 0; t <= T_STEPS; ++t) {
            if (wv < 2) {
                if (t < T_STEPS) {
                    const float4* hp = (const float4*)hfbuf[(t + 1) & 1];
                    const float xt = xbuf[t];
                    float p0 = fmaf(xt, wiA, bA), pp1 = 0.0f;
                    float q0 = fmaf(xt, wiB, bB), qq1 = 0.0f;
#pragma unroll
                    for (int q = 0; q < 16; q += 2) {
                        const float4 h0 = hp[q], h1 = hp[q + 1];
                        FMA4(p0,  W[q],          h0);
                        FMA4(pp1, W[q + 1],      h1);
                        FMA4(q0,  W[16 + q],     h0);
                        FMA4(qq1, W[16 + q + 1], h1);
                    }
                    const float z0 = p0 + pp1, z1 = q0 + qq1;
                    const float v0 = fast_sigm(z0);
                    const float v1 = (p1 == 0) ? fast_tanh(z1) : fast_sigm(z1);
                    const float o0 = __shfl_xor(v0, 32, 64);
                    const float o1 = __shfl_xor(v1, 32, 64);
                    if (p1 == 0) {
                        c1 = fmaf(o0, c1, v0 * v1);
                        hfbuf[t & 1][u1] = o1 * fast_tanh(c1);
                    }
                }
            } else {
                if (t >= 1) {
                    const int s = t - 1;
                    const float4* hf  = (const float4*)hfbuf[(t + 1) & 1];
                    const float4* h2p = (const float4*)h2buf[t & 1];
                    const uint4*  hrp = (const uint4*)(hr16 + s * 64);
                    float a0 = b2v, a1 = 0.0f, a2 = 0.0f, a3 = 0.0f;
#pragma unroll
                    for (int q = 0; q < 16; q += 2) {
                        FMA4(a0, W[q],     hf[q]);
                        FMA4(a1, W[q + 1], hf[q + 1]);
                    }
#pragma unroll
                    for (int q = 0; q < 8; ++q) {
                        const uint4 dv = hrp[q];
                        BF8(a2, a3, dv, W[16 + 2 * q], W[17 + 2 * q]);
                    }
#pragma unroll
                    for (int q = 0; q < 8; q += 2) {
                        FMA4(a0, W[32 + q],     h2p[q]);
                        FMA4(a1, W[32 + q + 1], h2p[q + 1]);
                    }
                    const float z = (a0 + a1) + (a2 + a3);
                    const float v = gate_fn(g2, z);
                    const float sf = __shfl_xor(v, 16, 64);
                    const float tg = __shfl_xor(v, 32, 64);
                    const float so = __shfl_xor(v, 48, 64);
                    if (g2 == 0) {
                        c2 = fmaf(sf, c2, v * tg);
                        h2buf[(t + 1) & 1][u2] = so * fast_tanh(c2);
                    }
                }
            }
            __syncthreads();
        }
    }

    {
        if (tid < 128) {
            const float4* hfl = (const float4*)hfbuf[1];
            const uint4*  hrl = (const uint4*)(hr16 + 511 * 64);
            const float4* wr  = (const float4*)(wih2r + tid * 128);
            float a0 = b2r[tid], a1 = 0.0f, a2 = 0.0f, a3 = 0.0f;
#pragma unroll
            for (int q = 0; q < 16; q += 2) {
                FMA4(a0, wr[q],     hfl[q]);
                FMA4(a1, wr[q + 1], hfl[q + 1]);
            }
#pragma unroll
            for (int q = 0; q < 8; ++q) {
                const uint4 dv = hrl[q];
                BF8(a2, a3, dv, wr[16 + 2 * q], wr[17 + 2 * q]);
            }
            const float z = (a0 + a1) + (a2 + a3);
            g2c[tid >> 5][tid & 31] = gate_fn(tid >> 5, z);
        }
        __syncthreads();
        if (tid < 32) {
            const float cr = g2c[0][tid] * g2c[2][tid];
            lastbuf[32 + tid] = g2c[3][tid] * fast_tanh(cr);
            lastbuf[tid]      = h2buf[1][tid];
        }
        __syncthreads();
        if (tid < 64) {
            const float4* lv = (const float4*)lastbuf;
            float acc = b_fc1[tid];
#pragma unroll
            for (int q = 0; q < 16; ++q) {
                const float4 wvv = *(const float4*)(w_fc1 + tid * 64 + q * 4);
                FMA4(acc, wvv, lv[q]);
            }
            float prod = fmaxf(acc, 0.0f) * w_out[tid];
#pragma unroll
            for (int s2 = 1; s2 < 64; s2 <<= 1) prod += __shfl_xor(prod, s2, 64);
            if (tid == 0) out[b] = fast_sigm(prod + b_out[0]);
        }
    }
}

// ---------------------------------------------------------------------------
extern "C" void kernel_launch(void* const* d_in, const int* in_sizes, int n_in,
                              void* d_out, int out_size, void* d_ws, size_t ws_size,
                              hipStream_t stream) {
    const float* x     = (const float*)d_in[0];
    const float* wih1f = (const float*)d_in[1];
    const float* whh1f = (const float*)d_in[2];
    const float* b1f   = (const float*)d_in[3];
    const float* wih1r = (const float*)d_in[4];
    const float* whh1r = (const float*)d_in[5];
    const float* b1r   = (const float*)d_in[6];
    const float* wih2f = (const float*)d_in[7];
    const float* whh2f = (const float*)d_in[8];
    const float* b2f   = (const float*)d_in[9];
    const float* wih2r = (const float*)d_in[10];
    // d_in[11] = whh2r unused: layer-2 reverse runs exactly one step from zero state
    const float* b2r   = (const float*)d_in[12];
    const float* w_fc1 = (const float*)d_in[13];
    const float* b_fc1 = (const float*)d_in[14];
    const float* w_out = (const float*)d_in[15];
    const float* b_out = (const float*)d_in[16];
    float* out = (float*)d_out;

    const size_t need = (size_t)NBLK * T_STEPS * NB * 64 * sizeof(unsigned short); // 64 MB
    if (ws_size >= need) {
        bilstm_mfma_kernel<<<dim3(NBLK), dim3(512), 0, stream>>>(
            x, wih1f, whh1f, b1f, wih1r, whh1r, b1r,
            wih2f, whh2f, b2f, wih2r, b2r,
            w_fc1, b_fc1, w_out, b_out,
            (unsigned short*)d_ws, out);
    } else {
        bilstm_fused_kernel<<<dim3(BATCH), dim3(256), 0, stream>>>(
            x, wih1f, whh1f, b1f, wih1r, whh1r, b1r,
            wih2f, whh2f, b2f, wih2r, b2r,
            w_fc1, b_fc1, w_out, b_out, out);
    }
}